// Round 8
// baseline (825.262 us; speedup 1.0000x reference)
//
#include <hip/hip_runtime.h>
#include <math.h>

#define WIN 11
#define PAD 5
#define TW 64              // tile width  = wave width
#define TH 64              // tile height (outputs)

struct GW { float g[WIN]; };

// ---------------------------------------------------------------------------
// Wave-autonomous SSIM tile: one wave streams a 64x64 output tile, NO
// block barriers. Per row: prefetched global load -> wave-private LDS row
// (74 float2) -> 11 ds_read_b64/lane -> H-conv -> 11-slot ring accumulators
// (incremental V-conv) -> one SSIM row emitted per step after priming.
// Cross-lane LDS handoff is ordered with __builtin_amdgcn_wave_barrier():
// without it the compiler's per-thread alias analysis may hoist the window
// reads above the row writes (R7's correctness failure).
// Ring math: h-row t feeds outputs o = t-10..t with weight g[t-o]; slot =
// o mod 11; output o completes at t = o+10, slot is then reset and reused.
// EMIT: L0 waves also pool rows pairwise into L1 (a=(P+Q)/2, b=(P-Q)/2).
// ---------------------------------------------------------------------------
template<bool EMIT>
__device__ __forceinline__ float ssim_wave_tile(
    const float* __restrict__ p1, const float* __restrict__ p2,
    int W, int X0, int Y0, const GW& gw, float2* __restrict__ rb,
    float* __restrict__ o1a, float* __restrict__ o1b, int Wout)
{
    const int lane = threadIdx.x & 63;
    const int gx = X0 + lane;
    const bool cval = gx < W;                              // false only for L4 lanes 32+
    const int hx   = (lane < 5) ? (X0 - 5 + lane) : (X0 + 59 + lane);
    const bool hval = (lane < 10) && ((unsigned)hx < (unsigned)W);
    const int hpos = (lane < 5) ? lane : (64 + lane);      // 0..4 | 69..73
    const int cpos = 5 + lane;

    float aMp[11], aSp[11], aMq[11], aSq[11];
#pragma unroll
    for (int s = 0; s < 11; ++s) { aMp[s] = 0.f; aSp[s] = 0.f; aMq[s] = 0.f; aSq[s] = 0.f; }

    float part = 0.f;
    float pprev = 0.f, qprev = 0.f;
    float a, b, ah, bh;

    auto LOAD = [&](int t, float& oa, float& ob, float& oah, float& obh) {
        int y = Y0 - PAD + t;
        oa = 0.f; ob = 0.f; oah = 0.f; obh = 0.f;
        if ((unsigned)y < (unsigned)W) {
            const float* r1 = p1 + (size_t)y * W;
            const float* r2 = p2 + (size_t)y * W;
            if (cval) { oa  = r1[gx]; ob  = r2[gx]; }
            if (hval) { oah = r1[hx]; obh = r2[hx]; }
        }
    };

    auto STEP = [&](int s, int t, bool prime) {
        // prefetch next row while computing this one
        float na, nb, nah, nbh;
        LOAD(t + 1, na, nb, nah, nbh);

        float p = a + b, q = a - b;
        float ph = ah + bh, qh = ah - bh;
        rb[cpos] = make_float2(p, q);
        if (lane < 10) rb[hpos] = make_float2(ph, qh);
        __builtin_amdgcn_wave_barrier();   // writes -> reads (cross-lane RAW)

        float hp = 0.f, hq = 0.f, hpp = 0.f, hqq = 0.f;
#pragma unroll
        for (int j = 0; j < WIN; ++j) {
            float2 v = rb[lane + j];
            float g = gw.g[j];
            hp  = fmaf(g, v.x, hp);
            hpp = fmaf(g, v.x * v.x, hpp);
            hq  = fmaf(g, v.y, hq);
            hqq = fmaf(g, v.y * v.y, hqq);
        }
        __builtin_amdgcn_wave_barrier();   // reads -> next row's writes (WAR)

#pragma unroll
        for (int mm = 0; mm < WIN; ++mm) {
            if (!prime || (s - mm) >= 0) {          // folds: s, mm, prime compile-time
                int sl = (s - mm + 11) % 11;
                float g = gw.g[mm];
                aMp[sl] = fmaf(g, hp,  aMp[sl]);
                aSp[sl] = fmaf(g, hpp, aSp[sl]);
                aMq[sl] = fmaf(g, hq,  aMq[sl]);
                aSq[sl] = fmaf(g, hqq, aSq[sl]);
            }
        }
        if (EMIT) {
            if (t >= 6 && t <= 68 && (t & 1) == 0) {   // pool rows (t-1, t)
                float sp_ = p + pprev, sq_ = q + qprev;
                float sp2 = sp_ + __shfl_down(sp_, 1, 64);
                float sq2 = sq_ + __shfl_down(sq_, 1, 64);
                if ((lane & 1) == 0) {
                    float P = sp2 * 0.25f, Q = sq2 * 0.25f;
                    int yo = (t - 6) >> 1;
                    size_t oo = (size_t)((Y0 >> 1) + yo) * Wout + ((X0 >> 1) + (lane >> 1));
                    o1a[oo] = (P + Q) * 0.5f;
                    o1b[oo] = (P - Q) * 0.5f;
                }
            }
            pprev = p; qprev = q;
        }
        if (t >= 10) {                               // output row o = t-10
            int e = (s + 1) % 11;
            int o = t - 10;
            bool yok = (unsigned)(Y0 + o) < (unsigned)W;   // false only for L4 tail
            float Mp = aMp[e], Sp_ = aSp[e], Mq = aMq[e], Sq_ = aSq[e];
            const float C1v = 1e-4f, C2v = 9e-4f;
            float A = Mp * Mp, B = Mq * Mq;
            float ABp = A + B, ABm = A - B;
            float SSp = Sp_ + Sq_, SSm = Sp_ - Sq_;
            float n1 = fmaf(0.5f, ABm, C1v);         // 2*m12 + C1
            float n2 = fmaf(0.5f, SSm - ABm, C2v);   // 2*s12 + C2
            float e1 = fmaf(0.5f, ABp, C1v);         // m1^2+m2^2 + C1
            float e2 = fmaf(0.5f, SSp - ABp, C2v);   // s1+s2 + C2
            float v = (n1 * n2) * __builtin_amdgcn_rcpf(e1 * e2);
            part += (cval && yok) ? v : 0.f;
            aMp[e] = 0.f; aSp[e] = 0.f; aMq[e] = 0.f; aSq[e] = 0.f;
        }
        a = na; b = nb; ah = nah; bh = nbh;
    };

    LOAD(0, a, b, ah, bh);

    // iter 0: t = 0..10 (priming, guarded ring updates; first emit at t=10)
#pragma unroll
    for (int s = 0; s <= 10; ++s) STEP(s, s, true);
    // middle: t = 11..65 (runtime outer loop keeps code size bounded)
    for (int i = 1; i <= 5; ++i) {
        int tb = 11 * i;
#pragma unroll
        for (int s = 0; s <= 10; ++s) STEP(s, tb + s, false);
    }
    // tail: t = 66..73 -> outputs o = 56..63
#pragma unroll
    for (int s = 0; s <= 7; ++s) STEP(s, 66 + s, false);

    return part;
}

// ---- L0: 8x8 tiles x 48 images = 3072 waves (768 blocks); emits L1 ----
__global__ __launch_bounds__(256, 4) void ssim_l0_kernel(
    const float* __restrict__ i1, const float* __restrict__ i2,
    float* __restrict__ a1, float* __restrict__ b1,
    double* __restrict__ acc, GW gw)
{
    __shared__ float2 rbs[4][80];
    const int wid = threadIdx.x >> 6;
    const int w = blockIdx.x * 4 + wid;
    const int img = w >> 6;
    const int tt = w & 63;
    const int tx = tt & 7, ty = tt >> 3;
    const size_t off  = (size_t)img * 512 * 512;
    const size_t ooff = (size_t)img * 256 * 256;

    float part = ssim_wave_tile<true>(i1 + off, i2 + off, 512, tx * TW, ty * TH,
                                      gw, rbs[wid], a1 + ooff, b1 + ooff, 256);
#pragma unroll
    for (int o = 32; o > 0; o >>= 1) part += __shfl_down(part, o, 64);
    if ((threadIdx.x & 63) == 0) atomicAdd(acc, (double)part);
}

// ---- L1..L4: 22 tiles per image pair = 1056 waves (264 blocks) ----
__global__ __launch_bounds__(256, 4) void ssim_rest_kernel(
    const float* __restrict__ a1, const float* __restrict__ b1,
    const float* __restrict__ a2, const float* __restrict__ b2,
    const float* __restrict__ a3, const float* __restrict__ b3,
    const float* __restrict__ a4, const float* __restrict__ b4,
    double* __restrict__ acc, GW gw)
{
    __shared__ float2 rbs[4][80];
    const int wid = threadIdx.x >> 6;
    const int w = blockIdx.x * 4 + wid;
    const int img = w / 22;
    const int r = w - img * 22;
    int lvl, tx, ty;
    if (r < 16)      { lvl = 1; tx = r & 3;        ty = r >> 2; }
    else if (r < 20) { lvl = 2; tx = (r - 16) & 1; ty = (r - 16) >> 1; }
    else if (r == 20){ lvl = 3; tx = 0; ty = 0; }
    else             { lvl = 4; tx = 0; ty = 0; }
    const int W = 512 >> lvl;
    const float* p1; const float* p2;
    switch (lvl) {
      case 1:  p1 = a1; p2 = b1; break;
      case 2:  p1 = a2; p2 = b2; break;
      case 3:  p1 = a3; p2 = b3; break;
      default: p1 = a4; p2 = b4; break;
    }
    const size_t off = (size_t)img * W * W;

    float part = ssim_wave_tile<false>(p1 + off, p2 + off, W, tx * TW, ty * TH,
                                       gw, rbs[wid], nullptr, nullptr, 0);
#pragma unroll
    for (int o = 32; o > 0; o >>= 1) part += __shfl_down(part, o, 64);
    if ((threadIdx.x & 63) == 0) atomicAdd(acc + lvl, (double)part);
}

// ---- pool L1 -> L2/L3/L4. Grid (16, 96). ----
__global__ __launch_bounds__(256) void pool_rest_kernel(
    const float* __restrict__ a1, const float* __restrict__ b1,
    float* __restrict__ a2, float* __restrict__ b2,
    float* __restrict__ a3, float* __restrict__ b3,
    float* __restrict__ a4, float* __restrict__ b4)
{
    __shared__ float l2[32][33];
    __shared__ float l3[16][17];
    const int tid = threadIdx.x;
    const int im = blockIdx.y;
    const int tb = blockIdx.x;
    const int tx = tb & 3, ty = tb >> 2;
    const bool second = im >= 48;
    const int ii = second ? im - 48 : im;
    const float* src = (second ? b1 : a1) + (size_t)ii * 256 * 256;
    float* o2 = (second ? b2 : a2) + (size_t)ii * 128 * 128;
    float* o3 = (second ? b3 : a3) + (size_t)ii * 64 * 64;
    float* o4 = (second ? b4 : a4) + (size_t)ii * 32 * 32;
    const int X0 = tx * 64, Y0 = ty * 64;

#pragma unroll
    for (int k = 0; k < 2; ++k) {
        int idx = tid + k * 256;
        int xp = idx & 15;
        int yo = idx >> 4;
        const float* rp = src + (size_t)(Y0 + 2 * yo) * 256 + (X0 + 4 * xp);
        float4 r0 = *(const float4*)rp;
        float4 r1 = *(const float4*)(rp + 256);
        float v0 = (r0.x + r0.y + r1.x + r1.y) * 0.25f;
        float v1 = (r0.z + r0.w + r1.z + r1.w) * 0.25f;
        l2[yo][2 * xp]     = v0;
        l2[yo][2 * xp + 1] = v1;
        float2* op = (float2*)(o2 + (size_t)((Y0 >> 1) + yo) * 128 + ((X0 >> 1) + 2 * xp));
        *op = make_float2(v0, v1);
    }
    __syncthreads();
    {
        int xo = tid & 15, yo = tid >> 4;
        if (yo < 16) {
            float v = (l2[2*yo][2*xo] + l2[2*yo][2*xo+1] +
                       l2[2*yo+1][2*xo] + l2[2*yo+1][2*xo+1]) * 0.25f;
            l3[yo][xo] = v;
            o3[(size_t)((Y0 >> 2) + yo) * 64 + ((X0 >> 2) + xo)] = v;
        }
    }
    __syncthreads();
    if (tid < 64) {
        int xo = tid & 7, yo = tid >> 3;
        float v = (l3[2*yo][2*xo] + l3[2*yo][2*xo+1] +
                   l3[2*yo+1][2*xo] + l3[2*yo+1][2*xo+1]) * 0.25f;
        o4[(size_t)((Y0 >> 3) + yo) * 32 + ((X0 >> 3) + xo)] = v;
    }
}

__global__ void final_kernel(const double* __restrict__ acc, float* __restrict__ out)
{
    double loss = 0.0;
#pragma unroll
    for (int l = 0; l < 5; ++l) {
        double cnt = 48.0 * (double)(512 >> l) * (double)(512 >> l);
        loss += 1.0 - acc[l] / cnt;
    }
    out[0] = (float)loss;
}

extern "C" void kernel_launch(void* const* d_in, const int* in_sizes, int n_in,
                              void* d_out, int out_size, void* d_ws, size_t ws_size,
                              hipStream_t stream)
{
    const float* img1 = (const float*)d_in[0];
    const float* img2 = (const float*)d_in[1];
    float* out = (float*)d_out;

    // 1D gaussian (sigma=1.5, k=11), matches reference construction
    GW gw;
    double gs[WIN], sum = 0.0;
    for (int i = 0; i < WIN; ++i) {
        double ax = (double)i - 5.0;
        gs[i] = exp(-(ax * ax) / 4.5);
        sum += gs[i];
    }
    for (int i = 0; i < WIN; ++i) gw.g[i] = (float)(gs[i] / sum);

    // workspace: 64B header (5 double acc), then pyramid
    double* acc = (double*)d_ws;
    float* base = (float*)((char*)d_ws + 64);
    const size_t n1 = 48ull * 256 * 256;
    const size_t n2 = 48ull * 128 * 128;
    const size_t n3 = 48ull * 64 * 64;
    const size_t n4 = 48ull * 32 * 32;
    float* a1 = base;      float* b1 = a1 + n1;
    float* a2 = b1 + n1;   float* b2 = a2 + n2;
    float* a3 = b2 + n2;   float* b3 = a3 + n3;
    float* a4 = b3 + n3;   float* b4 = a4 + n4;

    hipMemsetAsync(acc, 0, 5 * sizeof(double), stream);

    hipLaunchKernelGGL(ssim_l0_kernel, dim3(768), dim3(256), 0, stream,
                       img1, img2, a1, b1, acc, gw);

    hipLaunchKernelGGL(pool_rest_kernel, dim3(16, 96), dim3(256), 0, stream,
                       a1, b1, a2, b2, a3, b3, a4, b4);

    hipLaunchKernelGGL(ssim_rest_kernel, dim3(264), dim3(256), 0, stream,
                       a1, b1, a2, b2, a3, b3, a4, b4, acc, gw);

    hipLaunchKernelGGL(final_kernel, dim3(1), dim3(1), 0, stream, acc, out);
}

// Round 9
// 267.586 us; speedup vs baseline: 3.0841x; 3.0841x over previous
//
#include <hip/hip_runtime.h>
#include <math.h>

#define WIN 11
#define PAD 5
#define TW 64              // tile width  = wave width
#define TH 64              // tile height (outputs)

struct GW { float g[WIN]; };

// ---------------------------------------------------------------------------
// Wave-autonomous SSIM tile (R8 logic — verified correct — with a spill-proof
// loop shape). One wave streams a 64x64 output tile, no block barriers.
// Per row t: prefetched global load -> wave-private LDS row (74 float2,
// wave_barrier-ordered) -> 11 ds_read_b64/lane -> H-conv (hp,hpp,hq,hqq) ->
// SHIFT-REGISTER V-conv: slot k holds output o=t-10+k; each step adds
// g[10-k]*h (== g[t-o]), emits slot 0 when t>=10, shifts, zeroes slot 10.
// Uniform body => plain runtime t-loop (unroll 2 folds pool parity): only one
// load batch in flight, ~90 live VGPRs -- no scratch (R8's 975 MB of spill
// came from the 11x-unrolled ring hoisting all prefetches).
// EMIT: L0 waves also pool rows pairwise into L1 (a=(P+Q)/2, b=(P-Q)/2).
// ---------------------------------------------------------------------------
template<bool EMIT>
__device__ __forceinline__ float ssim_wave_tile(
    const float* __restrict__ p1, const float* __restrict__ p2,
    int W, int X0, int Y0, const GW& gw, float2* __restrict__ rb,
    float* __restrict__ o1a, float* __restrict__ o1b, int Wout)
{
    const int lane = threadIdx.x & 63;
    const int gx = X0 + lane;
    const bool cval = gx < W;                              // false only for L4 lanes 32+
    const int hx   = (lane < 5) ? (X0 - 5 + lane) : (X0 + 59 + lane);
    const bool hval = (lane < 10) && ((unsigned)hx < (unsigned)W);
    const int hpos = (lane < 5) ? lane : (64 + lane);      // 0..4 | 69..73
    const int cpos = 5 + lane;

    float vMp[11], vSp[11], vMq[11], vSq[11];
#pragma unroll
    for (int k = 0; k < 11; ++k) { vMp[k] = 0.f; vSp[k] = 0.f; vMq[k] = 0.f; vSq[k] = 0.f; }

    float part = 0.f;
    float pprev = 0.f, qprev = 0.f;
    float a, b, ah, bh;

    auto LOAD = [&](int t, float& oa, float& ob, float& oah, float& obh) {
        int y = Y0 - PAD + t;
        oa = 0.f; ob = 0.f; oah = 0.f; obh = 0.f;
        if ((unsigned)y < (unsigned)W) {
            const float* r1 = p1 + (size_t)y * W;
            const float* r2 = p2 + (size_t)y * W;
            if (cval) { oa  = r1[gx]; ob  = r2[gx]; }
            if (hval) { oah = r1[hx]; obh = r2[hx]; }
        }
    };

    LOAD(0, a, b, ah, bh);

#pragma unroll 2
    for (int t = 0; t < 74; ++t) {
        // prefetch next row while computing this one
        float na, nb, nah, nbh;
        LOAD(t + 1, na, nb, nah, nbh);

        float p = a + b, q = a - b;
        float ph = ah + bh, qh = ah - bh;
        rb[cpos] = make_float2(p, q);
        if (lane < 10) rb[hpos] = make_float2(ph, qh);
        __builtin_amdgcn_wave_barrier();   // writes -> reads (cross-lane RAW)

        float hp = 0.f, hq = 0.f, hpp = 0.f, hqq = 0.f;
#pragma unroll
        for (int j = 0; j < WIN; ++j) {
            float2 v = rb[lane + j];
            float g = gw.g[j];
            hp  = fmaf(g, v.x, hp);
            hpp = fmaf(g, v.x * v.x, hpp);
            hq  = fmaf(g, v.y, hq);
            hqq = fmaf(g, v.y * v.y, hqq);
        }
        __builtin_amdgcn_wave_barrier();   // reads -> next row's writes (WAR)

        // V-conv shift-register accumulate: slot k <- g[10-k]*h (== g[t-o])
#pragma unroll
        for (int k = 0; k < 11; ++k) {
            float g = gw.g[10 - k];
            vMp[k] = fmaf(g, hp,  vMp[k]);
            vSp[k] = fmaf(g, hpp, vSp[k]);
            vMq[k] = fmaf(g, hq,  vMq[k]);
            vSq[k] = fmaf(g, hqq, vSq[k]);
        }

        if (EMIT) {
            if (t >= 6 && t <= 68 && (t & 1) == 0) {   // pool rows (t-1, t)
                float sp_ = p + pprev, sq_ = q + qprev;
                float sp2 = sp_ + __shfl_down(sp_, 1, 64);
                float sq2 = sq_ + __shfl_down(sq_, 1, 64);
                if ((lane & 1) == 0) {
                    float P = sp2 * 0.25f, Q = sq2 * 0.25f;
                    int yo = (t - 6) >> 1;
                    size_t oo = (size_t)((Y0 >> 1) + yo) * Wout + ((X0 >> 1) + (lane >> 1));
                    o1a[oo] = (P + Q) * 0.5f;
                    o1b[oo] = (P - Q) * 0.5f;
                }
            }
            pprev = p; qprev = q;
        }

        if (t >= 10) {                               // output row o = t-10 from slot 0
            int o = t - 10;
            bool yok = (unsigned)(Y0 + o) < (unsigned)W;   // false only for L4 tail
            float Mp = vMp[0], Sp_ = vSp[0], Mq = vMq[0], Sq_ = vSq[0];
            const float C1v = 1e-4f, C2v = 9e-4f;
            float A = Mp * Mp, B = Mq * Mq;
            float ABp = A + B, ABm = A - B;
            float SSp = Sp_ + Sq_, SSm = Sp_ - Sq_;
            float n1 = fmaf(0.5f, ABm, C1v);         // 2*m12 + C1
            float n2 = fmaf(0.5f, SSm - ABm, C2v);   // 2*s12 + C2
            float e1 = fmaf(0.5f, ABp, C1v);         // m1^2+m2^2 + C1
            float e2 = fmaf(0.5f, SSp - ABp, C2v);   // s1+s2 + C2
            float v = (n1 * n2) * __builtin_amdgcn_rcpf(e1 * e2);
            part += (cval && yok) ? v : 0.f;
        }

        // shift down, clear slot 10
#pragma unroll
        for (int k = 0; k < 10; ++k) {
            vMp[k] = vMp[k + 1]; vSp[k] = vSp[k + 1];
            vMq[k] = vMq[k + 1]; vSq[k] = vSq[k + 1];
        }
        vMp[10] = 0.f; vSp[10] = 0.f; vMq[10] = 0.f; vSq[10] = 0.f;

        a = na; b = nb; ah = nah; bh = nbh;
    }

    return part;
}

// ---- L0: 8x8 tiles x 48 images = 3072 waves (768 blocks); emits L1 ----
__global__ __launch_bounds__(256, 4) void ssim_l0_kernel(
    const float* __restrict__ i1, const float* __restrict__ i2,
    float* __restrict__ a1, float* __restrict__ b1,
    double* __restrict__ acc, GW gw)
{
    __shared__ float2 rbs[4][80];
    const int wid = threadIdx.x >> 6;
    const int w = blockIdx.x * 4 + wid;
    const int img = w >> 6;
    const int tt = w & 63;
    const int tx = tt & 7, ty = tt >> 3;
    const size_t off  = (size_t)img * 512 * 512;
    const size_t ooff = (size_t)img * 256 * 256;

    float part = ssim_wave_tile<true>(i1 + off, i2 + off, 512, tx * TW, ty * TH,
                                      gw, rbs[wid], a1 + ooff, b1 + ooff, 256);
#pragma unroll
    for (int o = 32; o > 0; o >>= 1) part += __shfl_down(part, o, 64);
    if ((threadIdx.x & 63) == 0) atomicAdd(acc, (double)part);
}

// ---- L1..L4: 22 tiles per image pair = 1056 waves (264 blocks) ----
__global__ __launch_bounds__(256, 4) void ssim_rest_kernel(
    const float* __restrict__ a1, const float* __restrict__ b1,
    const float* __restrict__ a2, const float* __restrict__ b2,
    const float* __restrict__ a3, const float* __restrict__ b3,
    const float* __restrict__ a4, const float* __restrict__ b4,
    double* __restrict__ acc, GW gw)
{
    __shared__ float2 rbs[4][80];
    const int wid = threadIdx.x >> 6;
    const int w = blockIdx.x * 4 + wid;
    const int img = w / 22;
    const int r = w - img * 22;
    int lvl, tx, ty;
    if (r < 16)      { lvl = 1; tx = r & 3;        ty = r >> 2; }
    else if (r < 20) { lvl = 2; tx = (r - 16) & 1; ty = (r - 16) >> 1; }
    else if (r == 20){ lvl = 3; tx = 0; ty = 0; }
    else             { lvl = 4; tx = 0; ty = 0; }
    const int W = 512 >> lvl;
    const float* p1; const float* p2;
    switch (lvl) {
      case 1:  p1 = a1; p2 = b1; break;
      case 2:  p1 = a2; p2 = b2; break;
      case 3:  p1 = a3; p2 = b3; break;
      default: p1 = a4; p2 = b4; break;
    }
    const size_t off = (size_t)img * W * W;

    float part = ssim_wave_tile<false>(p1 + off, p2 + off, W, tx * TW, ty * TH,
                                       gw, rbs[wid], nullptr, nullptr, 0);
#pragma unroll
    for (int o = 32; o > 0; o >>= 1) part += __shfl_down(part, o, 64);
    if ((threadIdx.x & 63) == 0) atomicAdd(acc + lvl, (double)part);
}

// ---- pool L1 -> L2/L3/L4. Grid (16, 96). ----
__global__ __launch_bounds__(256) void pool_rest_kernel(
    const float* __restrict__ a1, const float* __restrict__ b1,
    float* __restrict__ a2, float* __restrict__ b2,
    float* __restrict__ a3, float* __restrict__ b3,
    float* __restrict__ a4, float* __restrict__ b4)
{
    __shared__ float l2[32][33];
    __shared__ float l3[16][17];
    const int tid = threadIdx.x;
    const int im = blockIdx.y;
    const int tb = blockIdx.x;
    const int tx = tb & 3, ty = tb >> 2;
    const bool second = im >= 48;
    const int ii = second ? im - 48 : im;
    const float* src = (second ? b1 : a1) + (size_t)ii * 256 * 256;
    float* o2 = (second ? b2 : a2) + (size_t)ii * 128 * 128;
    float* o3 = (second ? b3 : a3) + (size_t)ii * 64 * 64;
    float* o4 = (second ? b4 : a4) + (size_t)ii * 32 * 32;
    const int X0 = tx * 64, Y0 = ty * 64;

#pragma unroll
    for (int k = 0; k < 2; ++k) {
        int idx = tid + k * 256;
        int xp = idx & 15;
        int yo = idx >> 4;
        const float* rp = src + (size_t)(Y0 + 2 * yo) * 256 + (X0 + 4 * xp);
        float4 r0 = *(const float4*)rp;
        float4 r1 = *(const float4*)(rp + 256);
        float v0 = (r0.x + r0.y + r1.x + r1.y) * 0.25f;
        float v1 = (r0.z + r0.w + r1.z + r1.w) * 0.25f;
        l2[yo][2 * xp]     = v0;
        l2[yo][2 * xp + 1] = v1;
        float2* op = (float2*)(o2 + (size_t)((Y0 >> 1) + yo) * 128 + ((X0 >> 1) + 2 * xp));
        *op = make_float2(v0, v1);
    }
    __syncthreads();
    {
        int xo = tid & 15, yo = tid >> 4;
        if (yo < 16) {
            float v = (l2[2*yo][2*xo] + l2[2*yo][2*xo+1] +
                       l2[2*yo+1][2*xo] + l2[2*yo+1][2*xo+1]) * 0.25f;
            l3[yo][xo] = v;
            o3[(size_t)((Y0 >> 2) + yo) * 64 + ((X0 >> 2) + xo)] = v;
        }
    }
    __syncthreads();
    if (tid < 64) {
        int xo = tid & 7, yo = tid >> 3;
        float v = (l3[2*yo][2*xo] + l3[2*yo][2*xo+1] +
                   l3[2*yo+1][2*xo] + l3[2*yo+1][2*xo+1]) * 0.25f;
        o4[(size_t)((Y0 >> 3) + yo) * 32 + ((X0 >> 3) + xo)] = v;
    }
}

__global__ void final_kernel(const double* __restrict__ acc, float* __restrict__ out)
{
    double loss = 0.0;
#pragma unroll
    for (int l = 0; l < 5; ++l) {
        double cnt = 48.0 * (double)(512 >> l) * (double)(512 >> l);
        loss += 1.0 - acc[l] / cnt;
    }
    out[0] = (float)loss;
}

extern "C" void kernel_launch(void* const* d_in, const int* in_sizes, int n_in,
                              void* d_out, int out_size, void* d_ws, size_t ws_size,
                              hipStream_t stream)
{
    const float* img1 = (const float*)d_in[0];
    const float* img2 = (const float*)d_in[1];
    float* out = (float*)d_out;

    // 1D gaussian (sigma=1.5, k=11), matches reference construction
    GW gw;
    double gs[WIN], sum = 0.0;
    for (int i = 0; i < WIN; ++i) {
        double ax = (double)i - 5.0;
        gs[i] = exp(-(ax * ax) / 4.5);
        sum += gs[i];
    }
    for (int i = 0; i < WIN; ++i) gw.g[i] = (float)(gs[i] / sum);

    // workspace: 64B header (5 double acc), then pyramid
    double* acc = (double*)d_ws;
    float* base = (float*)((char*)d_ws + 64);
    const size_t n1 = 48ull * 256 * 256;
    const size_t n2 = 48ull * 128 * 128;
    const size_t n3 = 48ull * 64 * 64;
    const size_t n4 = 48ull * 32 * 32;
    float* a1 = base;      float* b1 = a1 + n1;
    float* a2 = b1 + n1;   float* b2 = a2 + n2;
    float* a3 = b2 + n2;   float* b3 = a3 + n3;
    float* a4 = b3 + n3;   float* b4 = a4 + n4;

    hipMemsetAsync(acc, 0, 5 * sizeof(double), stream);

    hipLaunchKernelGGL(ssim_l0_kernel, dim3(768), dim3(256), 0, stream,
                       img1, img2, a1, b1, acc, gw);

    hipLaunchKernelGGL(pool_rest_kernel, dim3(16, 96), dim3(256), 0, stream,
                       a1, b1, a2, b2, a3, b3, a4, b4);

    hipLaunchKernelGGL(ssim_rest_kernel, dim3(264), dim3(256), 0, stream,
                       a1, b1, a2, b2, a3, b3, a4, b4, acc, gw);

    hipLaunchKernelGGL(final_kernel, dim3(1), dim3(1), 0, stream, acc, out);
}